// Round 8
// baseline (306.968 us; speedup 1.0000x reference)
//
#include <hip/hip_runtime.h>
#include <math.h>

#define TWO_PI_F 6.283185307179586f
constexpr int B = 8;

// Workspace layout (float offsets). Proven budget >= 2,307,072 floats (r4).
constexpr size_t OFF_DWA = 0;        // 2048
constexpr size_t OFF_DPA = 2048;     // 4096
constexpr size_t OFF_DCA = 6144;     // 6144
constexpr size_t OFF_DWB = 12288;    // 2048   (ping-pong: topk1 out)
constexpr size_t OFF_DPB = 14336;    // 4096
constexpr size_t OFF_DCB = 18432;    // 6144
constexpr size_t OFF_CW  = 24576;    // 163840
constexpr size_t OFF_S   = 188416;   // 163840
constexpr size_t OFF_CPK = 352256;   // 1,638,400 fl = 163840 rows x 40 B
constexpr size_t OFF_TAIL= 1990656;  // 1024

typedef short s16x8 __attribute__((ext_vector_type(8)));
typedef float f32x4 __attribute__((ext_vector_type(4)));

__device__ __forceinline__ short f2bf(float x) {          // RNE fp32->bf16
    unsigned u = __float_as_uint(x);
    return (short)((u + 0x7fffu + ((u >> 16) & 1u)) >> 16);
}
__device__ __forceinline__ float bf2f(short s) {
    return __uint_as_float(((unsigned)(unsigned short)s) << 16);
}
__device__ __forceinline__ unsigned pk2(short a, short b) {
    return (unsigned)(unsigned short)a | ((unsigned)(unsigned short)b << 16);
}

// ============== pack: conv + norm factors + B-frag coeff rows (once) ========
// Row (20 shorts, 40 B): [h0..5, h0,h1 | h2..5, l0..3 | l4,l5, 0,0]
// == MFMA B-frag slots for C=[ch(6),ch(6),cl(6)] (18-term hi/lo scheme).
template <int CO, int CI, int ND, bool L0>
__global__ __launch_bounds__(256) void pack_kernel(
        const float* __restrict__ dw, const float* __restrict__ dp,
        const float* __restrict__ dc,
        const float* __restrict__ kw, const float* __restrict__ kp,
        const float* __restrict__ kc,
        const float* __restrict__ trp, const float* __restrict__ aip,
        float* __restrict__ sfA, float* __restrict__ cw,
        unsigned char* __restrict__ cpk, int* __restrict__ cnt) {
    constexpr int N = CI * ND * 5;
    constexpr int FAC = (CI < 2) ? 2 : CI;
    __shared__ float red[128];
    __shared__ float sfac[FAC], sscl[FAC];
    int bl = blockIdx.x, t = threadIdx.x;
    int b = bl / CO, co = bl % CO;
    size_t base = (size_t)bl * N;
    const float NHL2E = -0.72134752044448f;   // -0.5*log2(e)

    if (L0 && bl == 0 && t == 0) *cnt = 0;

    if (L0) {   // per-sample norm0 (in_c stride 4)
        float w0 = 0.f, c00 = 0.f, c01 = 0.f, c11 = 0.f;
        if (t < 128) {
            int idx = b * 128 + t;
            w0 = dw[idx];
            c00 = dc[4 * idx]; c01 = dc[4 * idx + 1]; c11 = dc[4 * idx + 3];
        }
        if (t < 128) red[t] = 0.5f * (c00 + c11);
        __syncthreads();
        for (int s = 64; s > 0; s >>= 1) { if (t < s) red[t] += red[t + s]; __syncthreads(); }
        float f = rsqrtf(red[0] / 128.f + 1e-8f);
        __syncthreads();
        float f2 = f * f;
        float det = (c00 * c11 - c01 * c01) * f2 * f2;
        if (t < 128) red[t] = fabsf(w0 * TWO_PI_F * sqrtf(fmaxf(det, 1e-12f)));
        __syncthreads();
        for (int s = 64; s > 0; s >>= 1) { if (t < s) red[t] += red[t + s]; __syncthreads(); }
        if (t == 0) {
            sfac[0] = f; sscl[0] = red[0] / 128.f + 1e-6f;
            if (co == 0) sfA[b] = f;
        }
    } else {    // deferred per-channel norm from topk partials
        if (t < CI) {
            float str = 0.f, sai = 0.f;
            for (int bb = 0; bb < B; ++bb) { str += trp[t * B + bb]; sai += aip[t * B + bb]; }
            float M = (float)(B * ND);
            float f = rsqrtf(str / M + 1e-8f);
            sfac[t] = f; sscl[t] = f * f * sai / M + 1e-6f;
            if (bl == 0) sfA[t] = f;
        }
    }
    __syncthreads();

    for (int n = t; n < N; n += 256) {
        int ci = n / (ND * 5);
        int rem = n % (ND * 5);
        int nd = rem / 5, nk = rem % 5;
        int di = (b * CI + ci) * ND + nd;
        int ki = (co * CI + ci) * 5 + nk;
        float f = sfac[ci], scl = sscl[ci], f2 = f * f;
        float wd = dw[di] / scl;
        float pd0 = f * dp[2 * di], pd1 = f * dp[2 * di + 1];
        float d00, d01, d11;
        if (L0) { d00 = f2 * dc[4 * di]; d01 = f2 * dc[4 * di + 1]; d11 = f2 * dc[4 * di + 3]; }
        else    { d00 = f2 * dc[3 * di]; d01 = f2 * dc[3 * di + 1]; d11 = f2 * dc[3 * di + 2]; }
        float wk = kw[ki], pk0 = kp[2 * ki], pk1 = kp[2 * ki + 1];
        float k00 = kc[4 * ki], k01 = kc[4 * ki + 1], k11 = kc[4 * ki + 3];
        float s00 = d00 + k00, s01 = d01 + k01, s11 = d11 + k11;
        float det_d = d00 * d11 - d01 * d01;
        float det_k = k00 * k11 - k01 * k01;
        float det_s = s00 * s11 - s01 * s01;
        float amp = TWO_PI_F * sqrtf(fmaxf(det_d * det_k / fmaxf(det_s, 1e-12f), 1e-20f));
        float w = wd * wk * amp;
        float q0 = pd0 + pk0, q1 = pd1 + pk1;
        cw[base + n] = w;

        float dinv = NHL2E / det_s;
        float A00 = s11 * dinv, A01h = -2.f * s01 * dinv, A11 = s00 * dinv;
        float u0 = -(2.f * A00 * q0 + A01h * q1);
        float u1 = -(A01h * q0 + 2.f * A11 * q1);
        float cj = (A00 * q0 + A01h * q1) * q0 + A11 * q1 * q1;
        float v[6] = {A00, A01h, A11, u0, u1, cj};
        short h[6], l[6];
#pragma unroll
        for (int q = 0; q < 6; ++q) { h[q] = f2bf(v[q]); l[q] = f2bf(v[q] - bf2f(h[q])); }
        unsigned ph01 = pk2(h[0], h[1]), ph23 = pk2(h[2], h[3]), ph45 = pk2(h[4], h[5]);
        unsigned pl01 = pk2(l[0], l[1]), pl23 = pk2(l[2], l[3]), pl45 = pk2(l[4], l[5]);
        uint2* row = (uint2*)(cpk + (base + n) * 40);
        row[0] = make_uint2(ph01, ph23);
        row[1] = make_uint2(ph45, ph01);
        row[2] = make_uint2(ph23, ph45);
        row[3] = make_uint2(pl01, pl23);
        row[4] = make_uint2(pl45, 0u);
    }
}

// ============== eval: LDS-free MFMA + exp2, global B-frag streaming =========
// block = (bl, i-super of 128). A-frags in registers once; B-frags streamed
// from global with an 8-deep register prefetch pipeline (covers ~250cyc L2).
template <int CO, int CI, int ND, bool L0>
__global__ __launch_bounds__(256) void eval_kernel(
        const float* __restrict__ dp, const float* __restrict__ kp,
        const float* __restrict__ cw, const unsigned char* __restrict__ cpk,
        const float* __restrict__ sfA, float* __restrict__ sbuf) {
    constexpr int N = CI * ND * 5, NSUP = N / 128, BLC = B * CO, NJT = N / 16;
    constexpr int PF = 8;                      // NJT = 40/80, both % 8 == 0
    int blk = blockIdx.x;
    int xg = blk & 7, yg = blk >> 3;           // XCD-affine: same-bl blocks on one XCD
    int bl = xg * (BLC / 8) + yg / NSUP;
    int sup = yg % NSUP;
    int b = bl / CO, co = bl % CO;
    int t = threadIdx.x, lane = t & 63, wave = t >> 6, col = lane & 15, quad = lane >> 4;
    size_t base = (size_t)bl * N;

    s16x8 afr[2]; f32x4 sacc[2];
#pragma unroll
    for (int n = 0; n < 2; ++n) {
        int irow = sup * 128 + (wave * 2 + n) * 16 + col;
        int ci = irow / (ND * 5);
        int rem = irow % (ND * 5);
        int nd = rem / 5, nk = rem % 5;
        int di = (b * CI + ci) * ND + nd;
        int ki = (co * CI + ci) * 5 + nk;
        float f = sfA[L0 ? b : ci];
        float p0 = f * dp[2 * di] + kp[2 * ki];
        float p1 = f * dp[2 * di + 1] + kp[2 * ki + 1];
        float v[6] = {p0 * p0, p0 * p1, p1 * p1, p0, p1, 1.0f};
        short h[6], l[6];
#pragma unroll
        for (int q = 0; q < 6; ++q) { h[q] = f2bf(v[q]); l[q] = f2bf(v[q] - bf2f(h[q])); }
        s16x8 a = (s16x8){0, 0, 0, 0, 0, 0, 0, 0};
        if (quad == 0)      a = (s16x8){h[0], h[1], h[2], h[3], h[4], h[5], l[0], l[1]};
        else if (quad == 1) a = (s16x8){l[2], l[3], l[4], l[5], h[0], h[1], h[2], h[3]};
        else if (quad == 2) a = (s16x8){h[4], h[5], 0, 0, 0, 0, 0, 0};
        afr[n] = a;
        sacc[n] = (f32x4){0.f, 0.f, 0.f, 0.f};
    }

    union U { uint2 u2[2]; unsigned u[4]; s16x8 s; };
    auto loadB = [&](int jt, s16x8& bf, float& wv) {
        int j = jt * 16 + col;
        wv = cw[base + j];
        const unsigned char* rp = cpk + ((size_t)(base + j)) * 40;
        U cv; cv.u[0] = cv.u[1] = cv.u[2] = cv.u[3] = 0u;
        if (quad == 0)      { cv.u2[0] = *(const uint2*)(rp);      cv.u2[1] = *(const uint2*)(rp + 8); }
        else if (quad == 1) { cv.u2[0] = *(const uint2*)(rp + 16); cv.u2[1] = *(const uint2*)(rp + 24); }
        else if (quad == 2) { cv.u[0] = *(const unsigned*)(rp + 32); }
        bf = cv.s;
    };

    s16x8 bq[PF]; float wq[PF];
#pragma unroll
    for (int k = 0; k < PF; ++k) loadB(k, bq[k], wq[k]);

#pragma unroll 8
    for (int jt = 0; jt < NJT; ++jt) {
        s16x8 bc = bq[jt & (PF - 1)];
        float wc = wq[jt & (PF - 1)];
        if (jt + PF < NJT) loadB(jt + PF, bq[jt & (PF - 1)], wq[jt & (PF - 1)]);
#pragma unroll
        for (int n = 0; n < 2; ++n) {
            f32x4 g = __builtin_amdgcn_mfma_f32_16x16x32_bf16(
                afr[n], bc, (f32x4){0.f, 0.f, 0.f, 0.f}, 0, 0, 0);
#pragma unroll
            for (int r = 0; r < 4; ++r)
                sacc[n][r] = fmaf(wc, __builtin_amdgcn_exp2f(g[r]), sacc[n][r]);
        }
    }

#pragma unroll
    for (int n = 0; n < 2; ++n) {
#pragma unroll
        for (int r = 0; r < 4; ++r) {
            float v = sacc[n][r];
            v += __shfl_xor(v, 1, 64);
            v += __shfl_xor(v, 2, 64);
            v += __shfl_xor(v, 4, 64);
            v += __shfl_xor(v, 8, 64);
            sacc[n][r] = v;
        }
        if (col == 0) {
            int ig = sup * 128 + (wave * 2 + n) * 16 + quad * 4;
            float4 st = make_float4(sacc[n][0], sacc[n][1], sacc[n][2], sacc[n][3]);
            *(float4*)&sbuf[base + ig] = st;
        }
    }
}

// ===== topk: relu-finish + argmax rounds + gather (pos/cov recomputed) ======
__device__ __forceinline__ unsigned int shfl_down_u32(unsigned int v, int off) {
    return (unsigned int)__shfl_down((int)v, off, 64);
}
template <int CO, int CI, int ND, bool L0>
__global__ __launch_bounds__(256) void topk_kernel(
        const float* __restrict__ sbuf, const float* __restrict__ cw,
        const float* __restrict__ dpi, const float* __restrict__ dci,
        const float* __restrict__ kp, const float* __restrict__ kc,
        const float* __restrict__ sfA,
        float* __restrict__ dwo, float* __restrict__ dpo, float* __restrict__ dco,
        float* __restrict__ trp, float* __restrict__ aip, int K) {
    constexpr int N = CI * ND * 5;
    __shared__ unsigned long long skey[1280];
    __shared__ float swn[1280];
    __shared__ unsigned long long wred[4];
    __shared__ unsigned long long bkk;
    __shared__ int sel[32];
    int blv = blockIdx.x;
    int b = blv / CO, l = blv % CO;
    size_t base = (size_t)blv * N;
    int t = threadIdx.x;

    for (int j = t; j < N; j += 256) {
        float s = sbuf[base + j];
        float denom = (fabsf(s) > 1e-6f) ? s : 1e-6f;
        float wnv = cw[base + j] * (fmaxf(s, 0.f) / denom);
        swn[j] = wnv;
        int ci = j / (ND * 5);
        int rem = j % (ND * 5);
        int nd = rem / 5, nk = rem % 5;
        int di = (b * CI + ci) * ND + nd;
        int ki = (l * CI + ci) * 5 + nk;
        float f = sfA[L0 ? b : ci], f2 = f * f;
        float c00, c01, c11;
        if (L0) {
            c00 = f2 * dci[4 * di] + kc[4 * ki];
            c01 = f2 * dci[4 * di + 1] + kc[4 * ki + 1];
            c11 = f2 * dci[4 * di + 3] + kc[4 * ki + 3];
        } else {
            c00 = f2 * dci[3 * di] + kc[4 * ki];
            c01 = f2 * dci[3 * di + 1] + kc[4 * ki + 1];
            c11 = f2 * dci[3 * di + 2] + kc[4 * ki + 3];
        }
        float det = c00 * c11 - c01 * c01;
        float sc = fabsf(wnv) * sqrtf(fmaxf(det, 1e-12f));
        unsigned int ub = __float_as_uint(sc) | 0x80000000u;
        skey[j] = ((unsigned long long)ub << 32) | (unsigned int)(~j);
    }
    __syncthreads();

    unsigned long long mk = 0ull;
    for (int j = t; j < N; j += 256) { unsigned long long v = skey[j]; if (v > mk) mk = v; }

    int lane = t & 63, wid = t >> 6;
    for (int r = 0; r < K; ++r) {
        unsigned int lo = (unsigned int)mk, hi = (unsigned int)(mk >> 32);
        for (int off = 32; off > 0; off >>= 1) {
            unsigned int olo = shfl_down_u32(lo, off);
            unsigned int ohi = shfl_down_u32(hi, off);
            if (ohi > hi || (ohi == hi && olo > lo)) { hi = ohi; lo = olo; }
        }
        if (lane == 0) wred[wid] = ((unsigned long long)hi << 32) | lo;
        __syncthreads();
        if (t == 0) {
            unsigned long long m = wred[0];
            for (int wq = 1; wq < 4; ++wq) if (wred[wq] > m) m = wred[wq];
            sel[r] = (int)(~(unsigned int)m);
            bkk = m;
        }
        __syncthreads();
        unsigned long long bkv = bkk;
        if (mk == bkv && mk != 0ull) {          // unique owner rescans
            int idx = (int)(~(unsigned int)bkv);
            skey[idx] = 0ull;
            mk = 0ull;
            for (int j = t; j < N; j += 256) { unsigned long long v = skey[j]; if (v > mk) mk = v; }
        }
    }

    float tr_c = 0.f, ai_c = 0.f;
    if (t < K) {
        int idx = sel[t];
        int ci = idx / (ND * 5);
        int rem = idx % (ND * 5);
        int nd = rem / 5, nk = rem % 5;
        int di = (b * CI + ci) * ND + nd;
        int ki = (l * CI + ci) * 5 + nk;
        float f = sfA[L0 ? b : ci], f2 = f * f;
        float q0 = f * dpi[2 * di] + kp[2 * ki];
        float q1 = f * dpi[2 * di + 1] + kp[2 * ki + 1];
        float c00, c01, c11;
        if (L0) {
            c00 = f2 * dci[4 * di] + kc[4 * ki];
            c01 = f2 * dci[4 * di + 1] + kc[4 * ki + 1];
            c11 = f2 * dci[4 * di + 3] + kc[4 * ki + 3];
        } else {
            c00 = f2 * dci[3 * di] + kc[4 * ki];
            c01 = f2 * dci[3 * di + 1] + kc[4 * ki + 1];
            c11 = f2 * dci[3 * di + 2] + kc[4 * ki + 3];
        }
        int o = blv * K + t;
        float wnv = swn[idx];
        dwo[o] = wnv;
        dpo[2 * o] = q0; dpo[2 * o + 1] = q1;
        dco[3 * o] = c00; dco[3 * o + 1] = c01; dco[3 * o + 2] = c11;
        tr_c = 0.5f * (c00 + c11);
        float det = c00 * c11 - c01 * c01;
        ai_c = fabsf(wnv * TWO_PI_F * sqrtf(fmaxf(det, 1e-12f)));
    }
    if (t < 64) {
        for (int off = 32; off > 0; off >>= 1) {
            tr_c += __shfl_down(tr_c, off, 64);
            ai_c += __shfl_down(ai_c, off, 64);
        }
        if (t == 0) { trp[l * B + b] = tr_c; aip[l * B + b] = ai_c; }
    }
}

// ==== final: per-(b,co) partials (cov recomputed); last block BN+softmax ====
__global__ __launch_bounds__(256) void final_kernel(
        const float* __restrict__ sbuf, const float* __restrict__ cw,
        const float* __restrict__ dci, const float* __restrict__ kc,
        const float* __restrict__ sfA,
        float* __restrict__ tbuf, float* __restrict__ ubuf, float* __restrict__ abuf,
        int* __restrict__ cnt, float* __restrict__ out) {
    constexpr int CO = 10, CI = 16, ND = 16, N = 1280;
    int blv = blockIdx.x;
    int b = blv / CO, l = blv % CO;
    size_t base = (size_t)blv * N;
    int t = threadIdx.x;
    __shared__ float r1[256], r2[256], r3[256];

    float tsum = 0.f, usum = 0.f, asum = 0.f;
    for (int n = t; n < N; n += 256) {
        float s = sbuf[base + n];
        float denom = (fabsf(s) > 1e-6f) ? s : 1e-6f;
        float wnv = cw[base + n] * (fmaxf(s, 0.f) / denom);
        int ci = n / (ND * 5);
        int rem = n % (ND * 5);
        int nd = rem / 5, nk = rem % 5;
        int di = (b * CI + ci) * ND + nd;
        int ki = (l * CI + ci) * 5 + nk;
        float f = sfA[ci], f2 = f * f;
        float c00 = f2 * dci[3 * di] + kc[4 * ki];
        float c01 = f2 * dci[3 * di + 1] + kc[4 * ki + 1];
        float c11 = f2 * dci[3 * di + 2] + kc[4 * ki + 3];
        tsum += 0.5f * (c00 + c11);
        float det = fmaxf(c00 * c11 - c01 * c01, 1e-30f);
        float integ = wnv * TWO_PI_F * sqrtf(det);
        usum += integ;
        asum += fabsf(integ);
    }
    r1[t] = tsum; r2[t] = usum; r3[t] = asum;
    __syncthreads();
    for (int s = 128; s > 0; s >>= 1) {
        if (t < s) { r1[t] += r1[t + s]; r2[t] += r2[t + s]; r3[t] += r3[t + s]; }
        __syncthreads();
    }
    __shared__ int lastf;
    if (t == 0) {
        tbuf[blv] = r1[0]; ubuf[blv] = r2[0]; abuf[blv] = r3[0];
        __threadfence();
        lastf = (atomicAdd(cnt, 1) == (int)gridDim.x - 1);
    }
    __syncthreads();
    if (!lastf) return;
    __threadfence();

    __shared__ float xs[80];
    __shared__ float xn[80];
    if (t < CO) {
        float tr = 0.f, a = 0.f;
        for (int bb = 0; bb < B; ++bb) { tr += tbuf[bb * CO + t]; a += abuf[bb * CO + t]; }
        float m = tr / (float)(B * N);
        float f = rsqrtf(m + 1e-8f);
        float f2 = f * f;
        float scale = f2 * a / (float)(B * N) + 1e-6f;
        for (int bb = 0; bb < B; ++bb) xs[bb * CO + t] = f2 * ubuf[bb * CO + t] / scale;
    }
    __syncthreads();
    if (t < CO) {
        float mu = 0.f;
        for (int bb = 0; bb < B; ++bb) mu += xs[bb * CO + t];
        mu *= 0.125f;
        float var = 0.f;
        for (int bb = 0; bb < B; ++bb) { float d = xs[bb * CO + t] - mu; var += d * d; }
        var *= 0.125f;
        float inv = rsqrtf(var + 1e-5f);
        for (int bb = 0; bb < B; ++bb) xn[bb * CO + t] = (xs[bb * CO + t] - mu) * inv;
    }
    __syncthreads();
    if (t < B) {
        float mx = -INFINITY;
        for (int c = 0; c < CO; ++c) mx = fmaxf(mx, xn[t * CO + c]);
        float se = 0.f;
        for (int c = 0; c < CO; ++c) se += expf(xn[t * CO + c] - mx);
        float lse = mx + logf(se);
        for (int c = 0; c < CO; ++c) out[t * CO + c] = xn[t * CO + c] - lse;
    }
}

extern "C" void kernel_launch(void* const* d_in, const int* in_sizes, int n_in,
                              void* d_out, int out_size, void* d_ws, size_t ws_size,
                              hipStream_t stream) {
    const float* in_w = (const float*)d_in[0];
    const float* in_p = (const float*)d_in[1];
    const float* in_c = (const float*)d_in[2];
    const float* kw[3] = {(const float*)d_in[3], (const float*)d_in[6], (const float*)d_in[9]};
    const float* kp[3] = {(const float*)d_in[4], (const float*)d_in[7], (const float*)d_in[10]};
    const float* kc[3] = {(const float*)d_in[5], (const float*)d_in[8], (const float*)d_in[11]};

    float* ws  = (float*)d_ws;
    float* dwA = ws + OFF_DWA; float* dpA = ws + OFF_DPA; float* dcA = ws + OFF_DCA;
    float* dwB = ws + OFF_DWB; float* dpB = ws + OFF_DPB; float* dcB = ws + OFF_DCB;
    float* cw  = ws + OFF_CW;
    float* sb  = ws + OFF_S;
    unsigned char* cpk = (unsigned char*)(ws + OFF_CPK);
    float* out = (float*)d_out;

    float* tail = ws + OFF_TAIL;
    float* trp0 = tail;          // 64
    float* aip0 = tail + 64;     // 64
    float* trp1 = tail + 128;    // 128
    float* aip1 = tail + 256;    // 128
    float* sfA0 = tail + 384;    // 8
    float* sfA1 = tail + 392;    // 8
    float* sfA2 = tail + 400;    // 16
    float* tbuf = tail + 416;    // 80
    float* ubuf = tail + 496;    // 80
    float* abuf = tail + 576;    // 80
    int*   cnt  = (int*)(tail + 656);

    // ---- layer 0: Co=8, Ci=1, Nd=128, N=640, K=32 ----
    pack_kernel<8, 1, 128, true><<<64, 256, 0, stream>>>(
        in_w, in_p, in_c, kw[0], kp[0], kc[0], nullptr, nullptr, sfA0, cw, cpk, cnt);
    eval_kernel<8, 1, 128, true><<<320, 256, 0, stream>>>(
        in_p, kp[0], cw, cpk, sfA0, sb);
    topk_kernel<8, 1, 128, true><<<64, 256, 0, stream>>>(
        sb, cw, in_p, in_c, kp[0], kc[0], sfA0, dwA, dpA, dcA, trp0, aip0, 32);
    // ---- layer 1: Co=16, Ci=8, Nd=32, N=1280, K=16 ----
    pack_kernel<16, 8, 32, false><<<128, 256, 0, stream>>>(
        dwA, dpA, dcA, kw[1], kp[1], kc[1], trp0, aip0, sfA1, cw, cpk, cnt);
    eval_kernel<16, 8, 32, false><<<1280, 256, 0, stream>>>(
        dpA, kp[1], cw, cpk, sfA1, sb);
    topk_kernel<16, 8, 32, false><<<128, 256, 0, stream>>>(
        sb, cw, dpA, dcA, kp[1], kc[1], sfA1, dwB, dpB, dcB, trp1, aip1, 16);
    // ---- layer 2: Co=10, Ci=16, Nd=16, N=1280, keep all ----
    pack_kernel<10, 16, 16, false><<<80, 256, 0, stream>>>(
        dwB, dpB, dcB, kw[2], kp[2], kc[2], trp1, aip1, sfA2, cw, cpk, cnt);
    eval_kernel<10, 16, 16, false><<<800, 256, 0, stream>>>(
        dpB, kp[2], cw, cpk, sfA2, sb);
    final_kernel<<<80, 256, 0, stream>>>(
        sb, cw, dcB, kc[2], sfA2, tbuf, ubuf, abuf, cnt, out);
}

// Round 10
// 252.107 us; speedup vs baseline: 1.2176x; 1.2176x over previous
//
#include <hip/hip_runtime.h>
#include <math.h>

#define TWO_PI_F 6.283185307179586f
constexpr int B = 8;

// Workspace layout (float offsets). Proven budget >= 2,306,048 floats (r4).
constexpr size_t OFF_DWA = 0;        // 2048
constexpr size_t OFF_DPA = 2048;     // 4096
constexpr size_t OFF_DCA = 6144;     // 6144
constexpr size_t OFF_DWB = 12288;    // 2048   (ping-pong: topk1 out)
constexpr size_t OFF_DPB = 14336;    // 4096
constexpr size_t OFF_DCB = 18432;    // 6144
constexpr size_t OFF_CW  = 24576;    // 163840
constexpr size_t OFF_S   = 188416;   // 163840
constexpr size_t OFF_CPK = 352256;   // 1,638,400 fl = 163840 rows x 40 B
constexpr size_t OFF_TAIL= 1990656;  // ~900

typedef short s16x8 __attribute__((ext_vector_type(8)));
typedef float f32x4 __attribute__((ext_vector_type(4)));

__device__ __forceinline__ short f2bf(float x) {          // RNE fp32->bf16
    unsigned u = __float_as_uint(x);
    return (short)((u + 0x7fffu + ((u >> 16) & 1u)) >> 16);
}
__device__ __forceinline__ float bf2f(short s) {
    return __uint_as_float(((unsigned)(unsigned short)s) << 16);
}
__device__ __forceinline__ unsigned pk2(short a, short b) {
    return (unsigned)(unsigned short)a | ((unsigned)(unsigned short)b << 16);
}
__device__ __forceinline__ unsigned int shfl_down_u32(unsigned int v, int off) {
    return (unsigned int)__shfl_down((int)v, off, 64);
}

// ============== pack: conv + norm factors + B-frag coeff rows (once) ========
// Row (20 shorts, 40 B): [h0..5, h0,h1 | h2..5, l0..3 | l4,l5, 0,0]
// == MFMA B-frag slots for C=[ch(6),ch(6),cl(6)] (18-term hi/lo scheme).
template <int CO, int CI, int ND, bool L0>
__global__ __launch_bounds__(256) void pack_kernel(
        const float* __restrict__ dw, const float* __restrict__ dp,
        const float* __restrict__ dc,
        const float* __restrict__ kw, const float* __restrict__ kp,
        const float* __restrict__ kc,
        const float* __restrict__ trp, const float* __restrict__ aip,
        float* __restrict__ sfA, float* __restrict__ cw,
        unsigned char* __restrict__ cpk, int* __restrict__ cnt) {
    constexpr int N = CI * ND * 5;
    constexpr int FAC = (CI < 2) ? 2 : CI;
    __shared__ float red[128];
    __shared__ float sfac[FAC], sscl[FAC];
    int bl = blockIdx.x, t = threadIdx.x;
    int b = bl / CO, co = bl % CO;
    size_t base = (size_t)bl * N;
    const float NHL2E = -0.72134752044448f;   // -0.5*log2(e)

    if (L0 && bl == 0 && t == 0) *cnt = 0;    // final-kernel counter reset

    if (L0) {   // per-sample norm0 (in_c stride 4)
        float w0 = 0.f, c00 = 0.f, c01 = 0.f, c11 = 0.f;
        if (t < 128) {
            int idx = b * 128 + t;
            w0 = dw[idx];
            c00 = dc[4 * idx]; c01 = dc[4 * idx + 1]; c11 = dc[4 * idx + 3];
        }
        if (t < 128) red[t] = 0.5f * (c00 + c11);
        __syncthreads();
        for (int s = 64; s > 0; s >>= 1) { if (t < s) red[t] += red[t + s]; __syncthreads(); }
        float f = rsqrtf(red[0] / 128.f + 1e-8f);
        __syncthreads();
        float f2 = f * f;
        float det = (c00 * c11 - c01 * c01) * f2 * f2;
        if (t < 128) red[t] = fabsf(w0 * TWO_PI_F * sqrtf(fmaxf(det, 1e-12f)));
        __syncthreads();
        for (int s = 64; s > 0; s >>= 1) { if (t < s) red[t] += red[t + s]; __syncthreads(); }
        if (t == 0) {
            sfac[0] = f; sscl[0] = red[0] / 128.f + 1e-6f;
            if (co == 0) sfA[b] = f;
        }
    } else {    // deferred per-channel norm from topk partials
        if (t < CI) {
            float str = 0.f, sai = 0.f;
            for (int bb = 0; bb < B; ++bb) { str += trp[t * B + bb]; sai += aip[t * B + bb]; }
            float M = (float)(B * ND);
            float f = rsqrtf(str / M + 1e-8f);
            sfac[t] = f; sscl[t] = f * f * sai / M + 1e-6f;
            if (bl == 0) sfA[t] = f;
        }
    }
    __syncthreads();

    for (int n = t; n < N; n += 256) {
        int ci = n / (ND * 5);
        int rem = n % (ND * 5);
        int nd = rem / 5, nk = rem % 5;
        int di = (b * CI + ci) * ND + nd;
        int ki = (co * CI + ci) * 5 + nk;
        float f = sfac[ci], scl = sscl[ci], f2 = f * f;
        float wd = dw[di] / scl;
        float pd0 = f * dp[2 * di], pd1 = f * dp[2 * di + 1];
        float d00, d01, d11;
        if (L0) { d00 = f2 * dc[4 * di]; d01 = f2 * dc[4 * di + 1]; d11 = f2 * dc[4 * di + 3]; }
        else    { d00 = f2 * dc[3 * di]; d01 = f2 * dc[3 * di + 1]; d11 = f2 * dc[3 * di + 2]; }
        float wk = kw[ki], pk0 = kp[2 * ki], pk1 = kp[2 * ki + 1];
        float k00 = kc[4 * ki], k01 = kc[4 * ki + 1], k11 = kc[4 * ki + 3];
        float s00 = d00 + k00, s01 = d01 + k01, s11 = d11 + k11;
        float det_d = d00 * d11 - d01 * d01;
        float det_k = k00 * k11 - k01 * k01;
        float det_s = s00 * s11 - s01 * s01;
        float amp = TWO_PI_F * sqrtf(fmaxf(det_d * det_k / fmaxf(det_s, 1e-12f), 1e-20f));
        float w = wd * wk * amp;
        float q0 = pd0 + pk0, q1 = pd1 + pk1;
        cw[base + n] = w;

        float dinv = NHL2E / det_s;
        float A00 = s11 * dinv, A01h = -2.f * s01 * dinv, A11 = s00 * dinv;
        float u0 = -(2.f * A00 * q0 + A01h * q1);
        float u1 = -(A01h * q0 + 2.f * A11 * q1);
        float cj = (A00 * q0 + A01h * q1) * q0 + A11 * q1 * q1;
        float v[6] = {A00, A01h, A11, u0, u1, cj};
        short h[6], l[6];
#pragma unroll
        for (int q = 0; q < 6; ++q) { h[q] = f2bf(v[q]); l[q] = f2bf(v[q] - bf2f(h[q])); }
        unsigned ph01 = pk2(h[0], h[1]), ph23 = pk2(h[2], h[3]), ph45 = pk2(h[4], h[5]);
        unsigned pl01 = pk2(l[0], l[1]), pl23 = pk2(l[2], l[3]), pl45 = pk2(l[4], l[5]);
        uint2* row = (uint2*)(cpk + (base + n) * 40);
        row[0] = make_uint2(ph01, ph23);
        row[1] = make_uint2(ph45, ph01);
        row[2] = make_uint2(ph23, ph45);
        row[3] = make_uint2(pl01, pl23);
        row[4] = make_uint2(pl45, 0u);
    }
}

// ============== eval: LDS-free MFMA + exp2, global B-frag streaming =========
// block = (bl, i-super of 128). A-frags in registers once; B-frags streamed
// with branch-free single-dwordx4 loads + PF=4 register ring.
template <int CO, int CI, int ND, bool L0>
__global__ __launch_bounds__(256) void eval_kernel(
        const float* __restrict__ dp, const float* __restrict__ kp,
        const float* __restrict__ cw, const unsigned char* __restrict__ cpk,
        const float* __restrict__ sfA, float* __restrict__ sbuf) {
    constexpr int N = CI * ND * 5, NSUP = N / 128, BLC = B * CO, NJT = N / 16;
    constexpr int PF = 4;                      // NJT = 40/80, both % 4 == 0
    int blk = blockIdx.x;
    int xg = blk & 7, yg = blk >> 3;           // XCD-affine L2-locality heuristic
    int bl = xg * (BLC / 8) + yg / NSUP;
    int sup = yg % NSUP;
    int b = bl / CO, co = bl % CO;
    int t = threadIdx.x, lane = t & 63, wave = t >> 6, col = lane & 15, quad = lane >> 4;
    size_t base = (size_t)bl * N;

    s16x8 afr[2]; f32x4 sacc[2];
#pragma unroll
    for (int n = 0; n < 2; ++n) {
        int irow = sup * 128 + (wave * 2 + n) * 16 + col;
        int ci = irow / (ND * 5);
        int rem = irow % (ND * 5);
        int nd = rem / 5, nk = rem % 5;
        int di = (b * CI + ci) * ND + nd;
        int ki = (co * CI + ci) * 5 + nk;
        float f = sfA[L0 ? b : ci];
        float p0 = f * dp[2 * di] + kp[2 * ki];
        float p1 = f * dp[2 * di + 1] + kp[2 * ki + 1];
        float v[6] = {p0 * p0, p0 * p1, p1 * p1, p0, p1, 1.0f};
        short h[6], l[6];
#pragma unroll
        for (int q = 0; q < 6; ++q) { h[q] = f2bf(v[q]); l[q] = f2bf(v[q] - bf2f(h[q])); }
        s16x8 a = (s16x8){0, 0, 0, 0, 0, 0, 0, 0};
        if (quad == 0)      a = (s16x8){h[0], h[1], h[2], h[3], h[4], h[5], l[0], l[1]};
        else if (quad == 1) a = (s16x8){l[2], l[3], l[4], l[5], h[0], h[1], h[2], h[3]};
        else if (quad == 2) a = (s16x8){h[4], h[5], 0, 0, 0, 0, 0, 0};
        afr[n] = a;
        sacc[n] = (f32x4){0.f, 0.f, 0.f, 0.f};
    }

    // Branch-free B-load: quad3 A-slots are zero and quad2 uses only its first
    // 4 slots, so lanes with quad>=2 read at row+32; the trailing 8 B land on
    // the next row / tail floats (finite) and multiply against zero A-slots.
    const unsigned char* rp = cpk + (base + col) * 40 + (quad < 2 ? quad * 16 : 32);
    const float* cwp = cw + base + col;
    union U { uint4 u4; s16x8 s; };

    uint4 bq[PF]; float wq[PF];
#pragma unroll
    for (int k = 0; k < PF; ++k) {
        bq[k] = *(const uint4*)(rp + (size_t)k * 640);
        wq[k] = cwp[k * 16];
    }
#pragma unroll 4
    for (int jt = 0; jt < NJT; ++jt) {
        int sl = jt & (PF - 1);
        U cv; cv.u4 = bq[sl];
        float wc = wq[sl];
        if (jt + PF < NJT) {
            bq[sl] = *(const uint4*)(rp + (size_t)(jt + PF) * 640);
            wq[sl] = cwp[(jt + PF) * 16];
        }
#pragma unroll
        for (int n = 0; n < 2; ++n) {
            f32x4 g = __builtin_amdgcn_mfma_f32_16x16x32_bf16(
                afr[n], cv.s, (f32x4){0.f, 0.f, 0.f, 0.f}, 0, 0, 0);
#pragma unroll
            for (int r = 0; r < 4; ++r)
                sacc[n][r] = fmaf(wc, __builtin_amdgcn_exp2f(g[r]), sacc[n][r]);
        }
    }

#pragma unroll
    for (int n = 0; n < 2; ++n) {
#pragma unroll
        for (int r = 0; r < 4; ++r) {
            float v = sacc[n][r];
            v += __shfl_xor(v, 1, 64);
            v += __shfl_xor(v, 2, 64);
            v += __shfl_xor(v, 4, 64);
            v += __shfl_xor(v, 8, 64);
            sacc[n][r] = v;
        }
        if (col == 0) {
            int ig = sup * 128 + (wave * 2 + n) * 16 + quad * 4;
            float4 st = make_float4(sacc[n][0], sacc[n][1], sacc[n][2], sacc[n][3]);
            *(float4*)&sbuf[base + ig] = st;
        }
    }
}

// ===== topk: relu-finish + argmax rounds + gather (pos/cov recomputed) ======
template <int CO, int CI, int ND, bool L0>
__global__ __launch_bounds__(256) void topk_kernel(
        const float* __restrict__ sbuf, const float* __restrict__ cw,
        const float* __restrict__ dpi, const float* __restrict__ dci,
        const float* __restrict__ kp, const float* __restrict__ kc,
        const float* __restrict__ sfA,
        float* __restrict__ dwo, float* __restrict__ dpo, float* __restrict__ dco,
        float* __restrict__ trp, float* __restrict__ aip, int K) {
    constexpr int N = CI * ND * 5;
    __shared__ unsigned long long skey[1280];
    __shared__ float swn[1280];
    __shared__ unsigned long long wred[4];
    __shared__ unsigned long long bkk;
    __shared__ int sel[32];
    int blv = blockIdx.x;
    int b = blv / CO, l = blv % CO;
    size_t base = (size_t)blv * N;
    int t = threadIdx.x;

    for (int j = t; j < N; j += 256) {
        float s = sbuf[base + j];
        float denom = (fabsf(s) > 1e-6f) ? s : 1e-6f;
        float wnv = cw[base + j] * (fmaxf(s, 0.f) / denom);
        swn[j] = wnv;
        int ci = j / (ND * 5);
        int rem = j % (ND * 5);
        int nd = rem / 5, nk = rem % 5;
        int di = (b * CI + ci) * ND + nd;
        int ki = (l * CI + ci) * 5 + nk;
        float f = sfA[L0 ? b : ci], f2 = f * f;
        float c00, c01, c11;
        if (L0) {
            c00 = f2 * dci[4 * di] + kc[4 * ki];
            c01 = f2 * dci[4 * di + 1] + kc[4 * ki + 1];
            c11 = f2 * dci[4 * di + 3] + kc[4 * ki + 3];
        } else {
            c00 = f2 * dci[3 * di] + kc[4 * ki];
            c01 = f2 * dci[3 * di + 1] + kc[4 * ki + 1];
            c11 = f2 * dci[3 * di + 2] + kc[4 * ki + 3];
        }
        float det = c00 * c11 - c01 * c01;
        float sc = fabsf(wnv) * sqrtf(fmaxf(det, 1e-12f));
        unsigned int ub = __float_as_uint(sc) | 0x80000000u;
        skey[j] = ((unsigned long long)ub << 32) | (unsigned int)(~j);
    }
    __syncthreads();

    unsigned long long mk = 0ull;
    for (int j = t; j < N; j += 256) { unsigned long long v = skey[j]; if (v > mk) mk = v; }

    int lane = t & 63, wid = t >> 6;
    for (int r = 0; r < K; ++r) {
        unsigned int lo = (unsigned int)mk, hi = (unsigned int)(mk >> 32);
        for (int off = 32; off > 0; off >>= 1) {
            unsigned int olo = shfl_down_u32(lo, off);
            unsigned int ohi = shfl_down_u32(hi, off);
            if (ohi > hi || (ohi == hi && olo > lo)) { hi = ohi; lo = olo; }
        }
        if (lane == 0) wred[wid] = ((unsigned long long)hi << 32) | lo;
        __syncthreads();
        if (t == 0) {
            unsigned long long m = wred[0];
            for (int wq = 1; wq < 4; ++wq) if (wred[wq] > m) m = wred[wq];
            sel[r] = (int)(~(unsigned int)m);
            bkk = m;
        }
        __syncthreads();
        unsigned long long bkv = bkk;
        if (mk == bkv && mk != 0ull) {          // unique owner rescans
            int idx = (int)(~(unsigned int)bkv);
            skey[idx] = 0ull;
            mk = 0ull;
            for (int j = t; j < N; j += 256) { unsigned long long v = skey[j]; if (v > mk) mk = v; }
        }
    }

    float tr_c = 0.f, ai_c = 0.f;
    if (t < K) {
        int idx = sel[t];
        int ci = idx / (ND * 5);
        int rem = idx % (ND * 5);
        int nd = rem / 5, nk = rem % 5;
        int di = (b * CI + ci) * ND + nd;
        int ki = (l * CI + ci) * 5 + nk;
        float f = sfA[L0 ? b : ci], f2 = f * f;
        float q0 = f * dpi[2 * di] + kp[2 * ki];
        float q1 = f * dpi[2 * di + 1] + kp[2 * ki + 1];
        float c00, c01, c11;
        if (L0) {
            c00 = f2 * dci[4 * di] + kc[4 * ki];
            c01 = f2 * dci[4 * di + 1] + kc[4 * ki + 1];
            c11 = f2 * dci[4 * di + 3] + kc[4 * ki + 3];
        } else {
            c00 = f2 * dci[3 * di] + kc[4 * ki];
            c01 = f2 * dci[3 * di + 1] + kc[4 * ki + 1];
            c11 = f2 * dci[3 * di + 2] + kc[4 * ki + 3];
        }
        int o = blv * K + t;
        float wnv = swn[idx];
        dwo[o] = wnv;
        dpo[2 * o] = q0; dpo[2 * o + 1] = q1;
        dco[3 * o] = c00; dco[3 * o + 1] = c01; dco[3 * o + 2] = c11;
        tr_c = 0.5f * (c00 + c11);
        float det = c00 * c11 - c01 * c01;
        ai_c = fabsf(wnv * TWO_PI_F * sqrtf(fmaxf(det, 1e-12f)));
    }
    if (t < 64) {
        for (int off = 32; off > 0; off >>= 1) {
            tr_c += __shfl_down(tr_c, off, 64);
            ai_c += __shfl_down(ai_c, off, 64);
        }
        if (t == 0) { trp[l * B + b] = tr_c; aip[l * B + b] = ai_c; }
    }
}

// ==== final: per-(b,co) partials (cov recomputed); last block BN+softmax ====
__global__ __launch_bounds__(256) void final_kernel(
        const float* __restrict__ sbuf, const float* __restrict__ cw,
        const float* __restrict__ dci, const float* __restrict__ kc,
        const float* __restrict__ sfA,
        float* __restrict__ tbuf, float* __restrict__ ubuf, float* __restrict__ abuf,
        int* __restrict__ cnt, float* __restrict__ out) {
    constexpr int CO = 10, CI = 16, ND = 16, N = 1280;
    int blv = blockIdx.x;
    int b = blv / CO, l = blv % CO;
    size_t base = (size_t)blv * N;
    int t = threadIdx.x;
    __shared__ float r1[256], r2[256], r3[256];

    float tsum = 0.f, usum = 0.f, asum = 0.f;
    for (int n = t; n < N; n += 256) {
        float s = sbuf[base + n];
        float denom = (fabsf(s) > 1e-6f) ? s : 1e-6f;
        float wnv = cw[base + n] * (fmaxf(s, 0.f) / denom);
        int ci = n / (ND * 5);
        int rem = n % (ND * 5);
        int nd = rem / 5, nk = rem % 5;
        int di = (b * CI + ci) * ND + nd;
        int ki = (l * CI + ci) * 5 + nk;
        float f = sfA[ci], f2 = f * f;
        float c00 = f2 * dci[3 * di] + kc[4 * ki];
        float c01 = f2 * dci[3 * di + 1] + kc[4 * ki + 1];
        float c11 = f2 * dci[3 * di + 2] + kc[4 * ki + 3];
        tsum += 0.5f * (c00 + c11);
        float det = fmaxf(c00 * c11 - c01 * c01, 1e-30f);
        float integ = wnv * TWO_PI_F * sqrtf(det);
        usum += integ;
        asum += fabsf(integ);
    }
    r1[t] = tsum; r2[t] = usum; r3[t] = asum;
    __syncthreads();
    for (int s = 128; s > 0; s >>= 1) {
        if (t < s) { r1[t] += r1[t + s]; r2[t] += r2[t + s]; r3[t] += r3[t + s]; }
        __syncthreads();
    }
    __shared__ int lastf;
    if (t == 0) {
        tbuf[blv] = r1[0]; ubuf[blv] = r2[0]; abuf[blv] = r3[0];
        __threadfence();
        lastf = (atomicAdd(cnt, 1) == (int)gridDim.x - 1);
    }
    __syncthreads();
    if (!lastf) return;
    __threadfence();

    __shared__ float xs[80];
    __shared__ float xn[80];
    if (t < CO) {
        float tr = 0.f, a = 0.f;
        for (int bb = 0; bb < B; ++bb) { tr += tbuf[bb * CO + t]; a += abuf[bb * CO + t]; }
        float m = tr / (float)(B * N);
        float f = rsqrtf(m + 1e-8f);
        float f2 = f * f;
        float scale = f2 * a / (float)(B * N) + 1e-6f;
        for (int bb = 0; bb < B; ++bb) xs[bb * CO + t] = f2 * ubuf[bb * CO + t] / scale;
    }
    __syncthreads();
    if (t < CO) {
        float mu = 0.f;
        for (int bb = 0; bb < B; ++bb) mu += xs[bb * CO + t];
        mu *= 0.125f;
        float var = 0.f;
        for (int bb = 0; bb < B; ++bb) { float d = xs[bb * CO + t] - mu; var += d * d; }
        var *= 0.125f;
        float inv = rsqrtf(var + 1e-5f);
        for (int bb = 0; bb < B; ++bb) xn[bb * CO + t] = (xs[bb * CO + t] - mu) * inv;
    }
    __syncthreads();
    if (t < B) {
        float mx = -INFINITY;
        for (int c = 0; c < CO; ++c) mx = fmaxf(mx, xn[t * CO + c]);
        float se = 0.f;
        for (int c = 0; c < CO; ++c) se += expf(xn[t * CO + c] - mx);
        float lse = mx + logf(se);
        for (int c = 0; c < CO; ++c) out[t * CO + c] = xn[t * CO + c] - lse;
    }
}

extern "C" void kernel_launch(void* const* d_in, const int* in_sizes, int n_in,
                              void* d_out, int out_size, void* d_ws, size_t ws_size,
                              hipStream_t stream) {
    const float* in_w = (const float*)d_in[0];
    const float* in_p = (const float*)d_in[1];
    const float* in_c = (const float*)d_in[2];
    const float* kw[3] = {(const float*)d_in[3], (const float*)d_in[6], (const float*)d_in[9]};
    const float* kp[3] = {(const float*)d_in[4], (const float*)d_in[7], (const float*)d_in[10]};
    const float* kc[3] = {(const float*)d_in[5], (const float*)d_in[8], (const float*)d_in[11]};

    float* ws  = (float*)d_ws;
    float* dwA = ws + OFF_DWA; float* dpA = ws + OFF_DPA; float* dcA = ws + OFF_DCA;
    float* dwB = ws + OFF_DWB; float* dpB = ws + OFF_DPB; float* dcB = ws + OFF_DCB;
    float* cw  = ws + OFF_CW;
    float* sb  = ws + OFF_S;
    unsigned char* cpk = (unsigned char*)(ws + OFF_CPK);
    float* out = (float*)d_out;

    float* tail = ws + OFF_TAIL;
    float* trp0 = tail;          // 64
    float* aip0 = tail + 64;     // 64
    float* trp1 = tail + 128;    // 128
    float* aip1 = tail + 256;    // 128
    float* sfA0 = tail + 384;    // 8
    float* sfA1 = tail + 392;    // 8
    float* sfA2 = tail + 400;    // 16
    float* tbuf = tail + 416;    // 80
    float* ubuf = tail + 496;    // 80
    float* abuf = tail + 576;    // 80
    int*   cnt  = (int*)(tail + 656);

    // ---- layer 0: Co=8, Ci=1, Nd=128, N=640, K=32 ----
    pack_kernel<8, 1, 128, true><<<64, 256, 0, stream>>>(
        in_w, in_p, in_c, kw[0], kp[0], kc[0], nullptr, nullptr, sfA0, cw, cpk, cnt);
    eval_kernel<8, 1, 128, true><<<320, 256, 0, stream>>>(
        in_p, kp[0], cw, cpk, sfA0, sb);
    topk_kernel<8, 1, 128, true><<<64, 256, 0, stream>>>(
        sb, cw, in_p, in_c, kp[0], kc[0], sfA0, dwA, dpA, dcA, trp0, aip0, 32);
    // ---- layer 1: Co=16, Ci=8, Nd=32, N=1280, K=16 ----
    pack_kernel<16, 8, 32, false><<<128, 256, 0, stream>>>(
        dwA, dpA, dcA, kw[1], kp[1], kc[1], trp0, aip0, sfA1, cw, cpk, cnt);
    eval_kernel<16, 8, 32, false><<<1280, 256, 0, stream>>>(
        dpA, kp[1], cw, cpk, sfA1, sb);
    topk_kernel<16, 8, 32, false><<<128, 256, 0, stream>>>(
        sb, cw, dpA, dcA, kp[1], kc[1], sfA1, dwB, dpB, dcB, trp1, aip1, 16);
    // ---- layer 2: Co=10, Ci=16, Nd=16, N=1280, keep all ----
    pack_kernel<10, 16, 16, false><<<80, 256, 0, stream>>>(
        dwB, dpB, dcB, kw[2], kp[2], kc[2], trp1, aip1, sfA2, cw, cpk, cnt);
    eval_kernel<10, 16, 16, false><<<800, 256, 0, stream>>>(
        dpB, kp[2], cw, cpk, sfA2, sb);
    final_kernel<<<80, 256, 0, stream>>>(
        sb, cw, dcB, kc[2], sfA2, tbuf, ubuf, abuf, cnt, out);
}